// Round 1
// 760.937 us; speedup vs baseline: 1.1619x; 1.1619x over previous
//
#include <hip/hip_runtime.h>
#include <stdint.h>

// Problem constants
constexpr int BB = 64;     // batch
constexpr int SS = 512;    // seq len
constexpr int DD = 256;    // emb dim
constexpr int HH = 256;    // hidden
constexpr int NHH = 4;     // heads
constexpr int KK = 1024;   // NH*H recurrent input dim

// HARD FACTS (r2-r9): VGPR budget = 128 iff static LDS forces <=2 WG/CU,
// else 64; never more. Step time == streamed_weight_bytes / 64 B/cyc (r7).
// Release/acquire cross-CU sync ~4us/step (r6). fp8/int8 weights break
// accuracy (r8).
//
// ROUND 11: rocprof showed VGPR_Count=52 on the R10 kernel -- the 64-VGPR
// weight slab was NOT resident (compiler rematerialized the const-restrict
// loads every step => 128 KB/CU/step streamed from L2; 32 CU/XCD x 128 KB /
// 0.85us ~= 4.8 TB/s = per-XCD L2 ceiling; r7's 64 B/cyc law was still in
// force). Fixes:
//  (a) amdgpu_waves_per_eu(4,4): pin the 16-wave/CU (2-WG) occupancy class
//      explicitly -> 128-VGPR budget; re-assert the "+v" pin INSIDE the
//      loop so w[] is loop-carried through VGPRs (keeping resident is now
//      strictly cheaper than spilling; demand ~99 regs <= 128).
//  (b) shorten the serial per-step chain: v-state moves into wave-0
//      registers (B3 + vbuf/zbuf eliminated; 2 barriers/step), U(s+1) and
//      the 4 gates prefetched during the poll window, h-update moved
//      off-path (pre-B2), publish of c(s+1) immediately after B2.
// Race audit: publish of c(k) at slot k&1/tag k+1 unchanged. Overwrite of
// slot k&1 by c(k+2) happens post-B2(k+1), which requires matvec(k+1),
// which requires peers' c(k+1), which peers publish only post-B2(k), i.e.
// after they consumed our c(k). Race-free (same induction as r6/R10).
constexpr int TT = 512;

typedef _Float16 f16;
typedef _Float16 f16x2 __attribute__((ext_vector_type(2)));

__device__ inline float dot2p(uint32_t a, uint32_t b, float c) {
  f16x2 av = __builtin_bit_cast(f16x2, a);
  f16x2 bv = __builtin_bit_cast(f16x2, b);
#if defined(__has_builtin)
#if __has_builtin(__builtin_amdgcn_fdot2)
  return __builtin_amdgcn_fdot2(av, bv, c, false);
#else
  return c + (float)av.x * (float)bv.x + (float)av.y * (float)bv.y;
#endif
#else
  return c + (float)av.x * (float)bv.x + (float)av.y * (float)bv.y;
#endif
}

__device__ inline float dot8(uint4 w, uint4 a, float c) {
  c = dot2p(w.x, a.x, c);
  c = dot2p(w.y, a.y, c);
  c = dot2p(w.z, a.z, c);
  c = dot2p(w.w, a.w, c);
  return c;
}

__device__ inline uint32_t pack2(float a, float b) {
  f16x2 v;
  v.x = (f16)a;
  v.y = (f16)b;
  return __builtin_bit_cast(uint32_t, v);
}

__device__ inline float fast_tanh(float x) {
  x = fminf(fmaxf(x, -15.f), 15.f);
  float e = __expf(2.f * x);
  return 1.f - 2.f / (e + 1.f);
}

// ---------------------------------------------------------------------------
// Prep A1: pack Wh [256,1024] fp32 -> Wq f16 for the v-form matvec.
// Wq[(p*16 + m)*512 + t]: t -> out=t&255 (n=out>>6, o_loc=out&63), ch2=t>>8.
// Holds Wh[64p + o_loc][256n + 128*ch2 + 8m .. +8) as 8 packed f16.
// ---------------------------------------------------------------------------
__global__ void k_pack_wq(const float* __restrict__ Wh, uint4* __restrict__ Wq) {
  int gid = blockIdx.x * blockDim.x + threadIdx.x;  // 32768
  int p = gid >> 13;
  int m = (gid >> 9) & 15;
  int t = gid & 511;
  int out = t & 255, ch2 = t >> 8;
  int n = out >> 6, o_loc = out & 63;
  const float* s = Wh + (64 * p + o_loc) * KK + 256 * n + 128 * ch2 + 8 * m;
  uint4 w;
  w.x = pack2(s[0], s[1]);
  w.y = pack2(s[2], s[3]);
  w.z = pack2(s[4], s[5]);
  w.w = pack2(s[6], s[7]);
  Wq[gid] = w;
}

// ---------------------------------------------------------------------------
// Prep A2/A3: transpose src[r, C] (r in [0,256)) -> dst[c*256 + r]
// ---------------------------------------------------------------------------
__global__ void k_transpose8(const float* __restrict__ src, float* __restrict__ dst,
                             int C, int total) {
  int gid = blockIdx.x * blockDim.x + threadIdx.x;
  if (gid >= total) return;
  int r = gid & 255, c = gid >> 8;
  dst[gid] = src[r * C + c];
}

// ---------------------------------------------------------------------------
// Prep B: U[row, o] = emb[src[row]] @ Wi^T + bi + bh (f16). Blocks beyond
// input_len[b] skipped.
// ---------------------------------------------------------------------------
__global__ __launch_bounds__(256) void k_precompute_u(
    const int* __restrict__ src, const float* __restrict__ emb,
    const float* __restrict__ WiT, const float* __restrict__ bi,
    const float* __restrict__ bh, const int* __restrict__ input_len,
    f16* __restrict__ U) {
  const int row0 = blockIdx.x * 32;
  const int b = row0 >> 9;
  if ((row0 & 511) >= input_len[b]) return;
  __shared__ float xs[32 * 256];
  __shared__ int srcs[32];
  const int tid = threadIdx.x;
  if (tid < 32) srcs[tid] = src[row0 + tid];
  __syncthreads();
  for (int i = tid; i < 32 * 256; i += 256) {
    int r = i >> 8, d = i & 255;
    xs[i] = emb[srcs[r] * DD + d];
  }
  __syncthreads();
  const int o = tid;
  float acc[32];
#pragma unroll
  for (int r = 0; r < 32; ++r) acc[r] = 0.f;
  for (int d0 = 0; d0 < 256; d0 += 8) {
    float w[8];
#pragma unroll
    for (int j = 0; j < 8; ++j) w[j] = WiT[(d0 + j) * 256 + o];  // coalesced
#pragma unroll
    for (int r = 0; r < 32; ++r) {
      const float4* xp = (const float4*)(xs + r * 256 + d0);  // broadcast
      float4 x0 = xp[0], x1 = xp[1];
      acc[r] += x0.x * w[0] + x0.y * w[1] + x0.z * w[2] + x0.w * w[3] +
                x1.x * w[4] + x1.y * w[5] + x1.z * w[6] + x1.w * w[7];
    }
  }
  float bias = bi[o] + bh[o];
#pragma unroll
  for (int r = 0; r < 32; ++r)
    U[(size_t)(row0 + r) * HH + o] = (f16)(acc[r] + bias);
}

// ---------------------------------------------------------------------------
// Main recurrence (v-form): 4 WGs (512 thr) per batch, blockIdx = p*64 + b
// (same-XCD heuristic; correctness is placement-independent). Thread t:
// out = t&255 (n=out>>6, o_loc=out&63), ch2 = t>>8 (input half).
// 16 resident uint4 weights/thread (pinned per-iteration). 60 KB LDS arena
// pins the 2-WG/CU occupancy class; waves_per_eu(4,4) pins the 128-reg
// budget. 256 WGs always co-resident (cap 512).
// Per-step schedule (2 barriers):
//   [poll window] wave0: prefetch U(s+1), 4 gates | waves1-3: gather c(s)
//   B1 | all: matvec -> partials; t<256: h-update (off-path) | B2
//   wave0: v-update (regs) -> z -> c(s+1) -> publish + cbuf write
// ---------------------------------------------------------------------------
__global__ void __attribute__((amdgpu_flat_work_group_size(512, 512),
                               amdgpu_waves_per_eu(4, 4)))
k_recurrence(
    const uint4* __restrict__ Wq, const f16* __restrict__ U,
    const float* __restrict__ fix_src, const int* __restrict__ input_len,
    const float* __restrict__ fc1T, const float* __restrict__ fc1_b,
    const float* __restrict__ fc2_W, const float* __restrict__ fc2_b,
    float* __restrict__ out, uint32_t* __restrict__ Cex,
    float* __restrict__ FPg, int* __restrict__ Flg) {
  __shared__ __align__(16) char arena[61440];  // 60 KB -> 2 WG/CU class
  f16* cbuf = (f16*)arena;                    // [0,512): c as f16[256]
  uint4* cvec = (uint4*)arena;                // same bytes, 32 uint4
  float* partials = (float*)(arena + 512);    // [512,2560): 512 floats
  float* hbuf = (float*)(arena + 2560);       // [2560,3584): 256 floats

  const int idx = blockIdx.x;
  const int b = idx & 63;
  const int p = idx >> 6;
  const int t = threadIdx.x;
  const int out_i = t & 255, ch2 = t >> 8;
  const int n = out_i >> 6, o_loc = out_i & 63;

  // one-time: this CU's 128 KB weight slab into VGPRs (64 regs)
  uint4 w[16];
  const uint4* wp = Wq + (p * 16) * TT + t;
#pragma unroll
  for (int m = 0; m < 16; ++m) w[m] = wp[m * TT];
#pragma unroll
  for (int m = 0; m < 16; ++m)
    asm volatile("" : "+v"(w[m].x), "+v"(w[m].y), "+v"(w[m].z), "+v"(w[m].w));

  // wave0 register state: v_n[64p + lane] for n=0..3
  float v0 = 0.f, v1 = 0.f, v2 = 0.f, v3 = 0.f;
  float h = 0.f;  // h_n[64p + o_loc] on threads t<256

  const int len = input_len[b];
  const f16* Ub = U + (size_t)b * SS * HH;
  const float* fsb = fix_src + b * SS;

  // prologue: c(0) = tanh(U(0)), publish slot 0 / tag 1. Own-region cbuf
  // write is ordered before the first matvec by B1 of iteration 0.
  if (t < 64) {
    float c0 = fast_tanh((float)Ub[64 * p + t]);
    f16 chv = (f16)c0;
    cbuf[64 * p + t] = chv;
    uint32_t dwp =
        ((uint32_t)__builtin_bit_cast(unsigned short, chv) << 16) | 1u;
    __hip_atomic_store(&Cex[b * 256 + p * 64 + t], dwp, __ATOMIC_RELAXED,
                       __HIP_MEMORY_SCOPE_AGENT);
  }

#pragma unroll 1
  for (int s = 0; s < len; ++s) {
    // residency pin: w[] must be live-in to every iteration in VGPRs
#pragma unroll
    for (int m = 0; m < 16; ++m)
      asm volatile("" : "+v"(w[m].x), "+v"(w[m].y), "+v"(w[m].z), "+v"(w[m].w));

    const int par = s & 1;
    const uint32_t tag = (uint32_t)((s + 1) & 0xffff);
    const float dval = fsb[s];
    float g = 0.f, gq1 = 0.f, gq2 = 0.f, gq3 = 0.f, ufn = 0.f;

    if (t < 64) {
      // prefetch U(s+1) (clamped: rows >= len are poison) + 4 gates,
      // all during the peers' poll window -> off the serial chain
      int sn = (s + 1 < len) ? (s + 1) : s;
      ufn = (float)Ub[(size_t)sn * HH + 64 * p + t];
      g   = 1.f / (1.f + __expf(0.f - dval));  // n=0 (own h-gate too)
      gq1 = 1.f / (1.f + __expf(3.f - dval));
      gq2 = 1.f / (1.f + __expf(6.f - dval));
      gq3 = 1.f / (1.f + __expf(9.f - dval));
    } else if (t < 256) {
      g = 1.f / (1.f + __expf((float)(3 * n) - dval));
      // waves 1..3: each gathers one peer's 64 self-tagged dwords
      int wv = t >> 6;       // 1,2,3
      int lane = t & 63;
      int q = (p + wv) & 3;  // peer CU
      uint32_t* addr = &Cex[((par * 64 + b) * 4 + q) * 64 + lane];
      uint32_t dw;
      do {
        dw = __hip_atomic_load(addr, __ATOMIC_RELAXED,
                               __HIP_MEMORY_SCOPE_AGENT);
      } while ((dw & 0xffffu) != tag);
      cbuf[64 * q + lane] =
          __builtin_bit_cast(f16, (unsigned short)(dw >> 16));
    }
    __syncthreads();  // B1: full c(s) in cbuf

    // matvec: thread covers (n, o_loc) x 128 inputs
    float acc = 0.f;
    const uint4* ap = cvec + ch2 * 16;  // wave-uniform -> broadcast
#pragma unroll
    for (int m = 0; m < 16; ++m) acc = dot8(w[m], ap[m], acc);
    partials[t] = acc;  // t = ch2*256 + out_i

    // h-update off the serial chain (reads own-region c(s); own region is
    // only overwritten post-B2)
    if (t < 256) {
      float cown = (float)cbuf[64 * p + o_loc];
      h = g * cown + (1.f - g) * h;
    }
    __syncthreads();  // B2: partials complete

    if (t < 64) {
      float w0 = partials[t]       + partials[256 + t];
      float w1 = partials[64 + t]  + partials[320 + t];
      float w2 = partials[128 + t] + partials[384 + t];
      float w3 = partials[192 + t] + partials[448 + t];
      v0 = g   * w0 + (1.f - g)   * v0;
      v1 = gq1 * w1 + (1.f - gq1) * v1;
      v2 = gq2 * w2 + (1.f - gq2) * v2;
      v3 = gq3 * w3 + (1.f - gq3) * v3;
      float c = fast_tanh(ufn + (v0 + v1 + v2 + v3));
      f16 chv = (f16)c;
      uint32_t dwp =
          ((uint32_t)__builtin_bit_cast(unsigned short, chv) << 16) |
          (uint32_t)((s + 2) & 0xffff);
      __hip_atomic_store(
          &Cex[(((s + 1) & 1) * 64 + b) * 256 + p * 64 + t], dwp,
          __ATOMIC_RELAXED, __HIP_MEMORY_SCOPE_AGENT);
      cbuf[64 * p + t] = chv;  // next-iter matvec reads after B1
    }
    // no B3: peer-region cbuf rewrites (next iter, pre-B1) only race with
    // reads that completed before B2; own-region rewrite is post-B2.
  }

  // ---- epilogue: fc1 partial over this CU's 256 k's, then one-time sync
  if (t < 256) hbuf[out_i] = h;  // hbuf[k_loc]: n=k_loc>>6, i=64p+(k_loc&63)
  __syncthreads();
  {
    float acc = 0.f;
#pragma unroll 4
    for (int r = 0; r < 128; ++r) {
      int k_loc = ch2 * 128 + r;
      int n2 = k_loc >> 6, il = k_loc & 63;
      int kg = n2 * 256 + 64 * p + il;
      acc += hbuf[k_loc] * fc1T[(size_t)kg * 256 + out_i];
    }
    partials[t] = acc;
  }
  __syncthreads();
  if (t < 256) FPg[(b * 4 + p) * 256 + out_i] =
      partials[out_i] + partials[256 + out_i];
  __syncthreads();  // barrier drains stores before flag
  if (t == 0)
    __hip_atomic_store(&Flg[b * 4 + p], 0x5A5A5A5A, __ATOMIC_RELEASE,
                       __HIP_MEMORY_SCOPE_AGENT);
  if (p != 0) return;
  if (t < 4 && t > 0) {
    while (__hip_atomic_load(&Flg[b * 4 + t], __ATOMIC_ACQUIRE,
                             __HIP_MEMORY_SCOPE_AGENT) != 0x5A5A5A5A) {
    }
  }
  __syncthreads();
  if (t < 256) {
    float pre = fc1_b[t];
#pragma unroll
    for (int q = 0; q < 4; ++q)
      pre += __hip_atomic_load(&FPg[(b * 4 + q) * 256 + t], __ATOMIC_RELAXED,
                               __HIP_MEMORY_SCOPE_AGENT);
    hbuf[t] = fast_tanh(pre);  // reuse as hid
  }
  __syncthreads();
  if (t < 64) {
    float p0 = 0.f, p1 = 0.f;
    for (int oi = t; oi < 256; oi += 64) {
      float hh = hbuf[oi];
      p0 += hh * fc2_W[oi];
      p1 += hh * fc2_W[256 + oi];
    }
#pragma unroll
    for (int off = 32; off; off >>= 1) {
      p0 += __shfl_down(p0, off);
      p1 += __shfl_down(p1, off);
    }
    if (t == 0) {
      out[b * 2 + 0] = p0 + fc2_b[0];
      out[b * 2 + 1] = p1 + fc2_b[1];
    }
  }
}

// ---------------------------------------------------------------------------
// Host launcher
// ws: [0,512K) Wq | [512K,768K) WiT | [768K,1792K) fc1T | [1792K,18176K) U
//     | [18176K,18304K) Cex | [18304K,18560K) FPg | [18560K,+1K) Flg
// Cex/Flg need no init: 0xAA poison never matches a tag (0xAAAA>512) or the
// 0x5A5A5A5A magic.
// ---------------------------------------------------------------------------
extern "C" void kernel_launch(void* const* d_in, const int* in_sizes, int n_in,
                              void* d_out, int out_size, void* d_ws, size_t ws_size,
                              hipStream_t stream) {
  const int* src = (const int*)d_in[0];
  const int* input_len = (const int*)d_in[1];
  const float* fix_src = (const float*)d_in[2];
  const float* emb = (const float*)d_in[3];
  const float* Wi = (const float*)d_in[4];
  const float* bi = (const float*)d_in[5];
  const float* Wh = (const float*)d_in[6];
  const float* bh = (const float*)d_in[7];
  const float* fc1_W = (const float*)d_in[8];
  const float* fc1_b = (const float*)d_in[9];
  const float* fc2_W = (const float*)d_in[10];
  const float* fc2_b = (const float*)d_in[11];
  float* out = (float*)d_out;

  char* ws = (char*)d_ws;
  uint4* Wq = (uint4*)(ws);                          // 512 KB
  float* WiT = (float*)(ws + (512ull << 10));        // 256 KB
  float* fc1T = (float*)(ws + (768ull << 10));       // 1 MB
  f16* U = (f16*)(ws + (1792ull << 10));             // 16 MB
  uint32_t* Cex = (uint32_t*)(ws + (18176ull << 10)); // 128 KB
  float* FPg = (float*)(ws + (18304ull << 10));      // 256 KB
  int* Flg = (int*)(ws + (18560ull << 10));          // 1 KB
  const size_t needed = (18561ull << 10);
  if (ws_size < needed) return;

  k_pack_wq<<<128, 256, 0, stream>>>(Wh, Wq);
  k_transpose8<<<(65536 + 255) / 256, 256, 0, stream>>>(Wi, WiT, 256, 65536);
  k_transpose8<<<(262144 + 255) / 256, 256, 0, stream>>>(fc1_W, fc1T, 1024, 262144);
  k_precompute_u<<<BB * SS / 32, 256, 0, stream>>>(src, emb, WiT, bi, bh,
                                                   input_len, U);
  k_recurrence<<<BB * 4, TT, 0, stream>>>(Wq, U, fix_src, input_len, fc1T,
                                          fc1_b, fc2_W, fc2_b, out, Cex, FPg,
                                          Flg);
}